// Round 5
// baseline (181.164 us; speedup 1.0000x reference)
//
#include <hip/hip_runtime.h>
#include <hip/hip_bf16.h>

#define N_NODES 100000
#define N_EDGES 1600000
#define IN_DIM 256
#define OUT_DIM 128

typedef __attribute__((ext_vector_type(4))) float f32x4;
typedef __attribute__((ext_vector_type(8))) short s16x8;

__device__ inline unsigned short f2bf_us(float f) {
    union { __hip_bfloat16 h; unsigned short u; } v;
    v.h = __float2bfloat16(f);   // RNE, compiles to v_cvt cvt
    return v.u;
}

__device__ inline s16x8 pack8(const float4& a, const float4& b) {
    union { s16x8 v; __hip_bfloat162 h[4]; } u;
    u.h[0] = __float22bfloat162_rn(make_float2(a.x, a.y));
    u.h[1] = __float22bfloat162_rn(make_float2(a.z, a.w));
    u.h[2] = __float22bfloat162_rn(make_float2(b.x, b.y));
    u.h[3] = __float22bfloat162_rn(make_float2(b.z, b.w));
    return u.v;
}

// ---------------- WT = bf16(W^T) : [col][k], 128x256 ----------------
__global__ __launch_bounds__(256)
void wt_kernel(const float* __restrict__ W, unsigned short* __restrict__ WT) {
    const int t = blockIdx.x * 256 + threadIdx.x;   // 0..32767
    const int k = t >> 7;
    const int c = t & 127;
    WT[c * IN_DIM + k] = f2bf_us(W[t]);
}

// ---------------- GEMM: HWp(bf16, slab-major) = bf16(H) @ bf16(W) -------------
// NO LDS. 256 threads = 4 waves; block covers 128 rows. B-frags from WT
// (64 KB, L2-resident). Output layout: 8 column-slabs HWp[n][row][16],
// n = MFMA tile index = column block (cols 16n..16n+15). Slab = 3.2 MB.
__global__ __launch_bounds__(256)
void gemm_mfma_kernel(const float* __restrict__ H,
                      const unsigned short* __restrict__ WT,
                      unsigned short* __restrict__ HWp) {
    const int tid  = threadIdx.x;
    const int wid  = tid >> 6;
    const int lane = tid & 63;
    const int lrow = lane & 15;
    const int kblk = lane >> 4;
    const int wrow = blockIdx.x * 128 + wid * 32;

    int r0 = wrow + lrow;       if (r0 >= N_NODES) r0 = N_NODES - 1;
    int r1 = wrow + lrow + 16;  if (r1 >= N_NODES) r1 = N_NODES - 1;
    const float* p0 = H + (size_t)r0 * IN_DIM + kblk * 8;
    const float* p1 = H + (size_t)r1 * IN_DIM + kblk * 8;

    f32x4 acc[2][8] = {};

    float4 c00 = *(const float4*)(p0);
    float4 c01 = *(const float4*)(p0 + 4);
    float4 c10 = *(const float4*)(p1);
    float4 c11 = *(const float4*)(p1 + 4);

    #pragma unroll
    for (int kc = 0; kc < 8; ++kc) {
        const s16x8 fa0 = pack8(c00, c01);
        const s16x8 fa1 = pack8(c10, c11);
        if (kc < 7) {
            const float* q0 = p0 + (kc + 1) * 32;
            const float* q1 = p1 + (kc + 1) * 32;
            c00 = *(const float4*)(q0);
            c01 = *(const float4*)(q0 + 4);
            c10 = *(const float4*)(q1);
            c11 = *(const float4*)(q1 + 4);
        }
        const int kbase = kc * 32 + kblk * 8;
        #pragma unroll
        for (int n = 0; n < 8; ++n) {
            const s16x8 fb =
                *(const s16x8*)(WT + (size_t)(n * 16 + lrow) * IN_DIM + kbase);
            acc[0][n] = __builtin_amdgcn_mfma_f32_16x16x32_bf16(fa0, fb, acc[0][n], 0, 0, 0);
            acc[1][n] = __builtin_amdgcn_mfma_f32_16x16x32_bf16(fa1, fb, acc[1][n], 0, 0, 0);
        }
    }

    // D layout: col-within-tile = lane&15, row = (lane>>4)*4 + reg
    #pragma unroll
    for (int mt = 0; mt < 2; ++mt) {
        #pragma unroll
        for (int r = 0; r < 4; ++r) {
            const int grow = wrow + mt * 16 + (lane >> 4) * 4 + r;
            if (grow < N_NODES) {
                #pragma unroll
                for (int n = 0; n < 8; ++n)
                    HWp[(size_t)n * (N_NODES * 16) + (size_t)grow * 16 + (lane & 15)] =
                        f2bf_us(acc[mt][n][r]);
            }
        }
    }
}

// ---------------- row_ptr from sorted dst ----------------
__global__ __launch_bounds__(256)
void rowptr_kernel(const int* __restrict__ dst, int* __restrict__ row_ptr) {
    const int e = blockIdx.x * blockDim.x + threadIdx.x;
    if (e > N_EDGES) return;
    if (e == N_EDGES) {
        for (int n = dst[N_EDGES - 1] + 1; n <= N_NODES; ++n) row_ptr[n] = N_EDGES;
        return;
    }
    const int d = dst[e];
    const int dprev = (e == 0) ? -1 : dst[e - 1];
    for (int n = dprev + 1; n <= d; ++n) row_ptr[n] = e;
}

// ---------------- SpMM: out = A @ HW + bias, 8 column passes ----------------
// pass p = blockIdx.y gathers ONLY slab p (3.2 MB, per-XCD-L2-resident).
// Wave = 8 groups x 8 lanes; group = 1 node; lane = 1 uint (2 bf16 cols).
// Disjoint column writes per pass -> atomic-free, deterministic.
__global__ __launch_bounds__(256)
void spmm_pass_kernel(const unsigned int* __restrict__ HWpu,
                      const float* __restrict__ vals,
                      const int* __restrict__ src,
                      const int* __restrict__ row_ptr,
                      const float* __restrict__ bias,
                      float* __restrict__ out) {
    const int p    = blockIdx.y;
    const int tid  = threadIdx.x;
    const int node = blockIdx.x * 32 + (tid >> 3);
    const int sub  = tid & 7;
    if (node >= N_NODES) return;

    const unsigned int* __restrict__ slab = HWpu + (size_t)p * (N_NODES * 8);

    const int lo = row_ptr[node];
    const int hi = row_ptr[node + 1];

    float ax = 0.f, ay = 0.f;
    int e = lo;
    for (; e + 8 <= hi; e += 8) {
        int s[8]; float v[8];
        #pragma unroll
        for (int j = 0; j < 8; ++j) { s[j] = src[e + j]; v[j] = vals[e + j]; }
        unsigned u[8];
        #pragma unroll
        for (int j = 0; j < 8; ++j) u[j] = slab[(size_t)s[j] * 8 + sub];
        #pragma unroll
        for (int j = 0; j < 8; ++j) {
            ax = fmaf(__uint_as_float(u[j] << 16), v[j], ax);
            ay = fmaf(__uint_as_float(u[j] & 0xffff0000u), v[j], ay);
        }
    }
    if (e + 4 <= hi) {
        int s[4]; float v[4];
        #pragma unroll
        for (int j = 0; j < 4; ++j) { s[j] = src[e + j]; v[j] = vals[e + j]; }
        unsigned u[4];
        #pragma unroll
        for (int j = 0; j < 4; ++j) u[j] = slab[(size_t)s[j] * 8 + sub];
        #pragma unroll
        for (int j = 0; j < 4; ++j) {
            ax = fmaf(__uint_as_float(u[j] << 16), v[j], ax);
            ay = fmaf(__uint_as_float(u[j] & 0xffff0000u), v[j], ay);
        }
        e += 4;
    }
    for (; e < hi; ++e) {
        const unsigned u = slab[(size_t)src[e] * 8 + sub];
        const float v = vals[e];
        ax = fmaf(__uint_as_float(u << 16), v, ax);
        ay = fmaf(__uint_as_float(u & 0xffff0000u), v, ay);
    }

    const float2 b2 = ((const float2*)bias)[p * 8 + sub];
    ((float2*)out)[(size_t)node * 64 + p * 8 + sub] =
        make_float2(ax + b2.x, ay + b2.y);
}

extern "C" void kernel_launch(void* const* d_in, const int* in_sizes, int n_in,
                              void* d_out, int out_size, void* d_ws, size_t ws_size,
                              hipStream_t stream) {
    const float* H    = (const float*)d_in[0];
    const float* W    = (const float*)d_in[1];
    const float* bias = (const float*)d_in[2];
    const float* vals = (const float*)d_in[3];
    const int*   src  = (const int*)d_in[4];
    const int*   dst  = (const int*)d_in[5];
    float* out = (float*)d_out;

    // ws: HWp bf16 slabs [0, 25.6e6) | row_ptr | WT (128B aligned)
    unsigned short* HWp = (unsigned short*)d_ws;
    const size_t hw_bytes = (size_t)N_NODES * OUT_DIM * sizeof(unsigned short);
    int* row_ptr = (int*)((char*)d_ws + hw_bytes);
    size_t wt_off = hw_bytes + (size_t)(N_NODES + 1) * sizeof(int);
    wt_off = (wt_off + 127) & ~(size_t)127;
    unsigned short* WT = (unsigned short*)((char*)d_ws + wt_off);

    wt_kernel<<<dim3((IN_DIM * OUT_DIM) / 256), dim3(256), 0, stream>>>(W, WT);
    rowptr_kernel<<<dim3((N_EDGES + 256) / 256), dim3(256), 0, stream>>>(dst, row_ptr);
    gemm_mfma_kernel<<<dim3((N_NODES + 127) / 128), dim3(256), 0, stream>>>(H, WT, HWp);
    spmm_pass_kernel<<<dim3((N_NODES + 31) / 32, 8), dim3(256), 0, stream>>>(
        (const unsigned int*)HWp, vals, src, row_ptr, bias, out);
}

// Round 6
// 173.574 us; speedup vs baseline: 1.0437x; 1.0437x over previous
//
#include <hip/hip_runtime.h>
#include <hip/hip_bf16.h>

#define N_NODES 100000
#define N_EDGES 1600000
#define IN_DIM 256
#define OUT_DIM 128

typedef __attribute__((ext_vector_type(4))) float f32x4;
typedef __attribute__((ext_vector_type(8))) short s16x8;

__device__ inline unsigned short f2bf_us(float f) {
    union { __hip_bfloat16 h; unsigned short u; } v;
    v.h = __float2bfloat16(f);
    return v.u;
}

__device__ inline s16x8 pack8(const float4& a, const float4& b) {
    union { s16x8 v; __hip_bfloat162 h[4]; } u;
    u.h[0] = __float22bfloat162_rn(make_float2(a.x, a.y));
    u.h[1] = __float22bfloat162_rn(make_float2(a.z, a.w));
    u.h[2] = __float22bfloat162_rn(make_float2(b.x, b.y));
    u.h[3] = __float22bfloat162_rn(make_float2(b.z, b.w));
    return u.v;
}

// ---------------- WT = bf16(W^T) : [col][k], 128x256 ----------------
__global__ __launch_bounds__(256)
void wt_kernel(const float* __restrict__ W, unsigned short* __restrict__ WT) {
    const int t = blockIdx.x * 256 + threadIdx.x;   // 0..32767
    const int k = t >> 7;
    const int c = t & 127;
    WT[c * IN_DIM + k] = f2bf_us(W[t]);
}

// ---------------- GEMM: HWp(bf16, slab-major) = bf16(H) @ bf16(W) -------------
// NO LDS (graph-replay corruption seen with 67KB LDS in R3). 4 waves/block,
// 128 rows/block. B-frags from WT (64 KB, L2-resident). Output: 8 column
// slabs HWp[n][row][16], slab = 3.2 MB.
__global__ __launch_bounds__(256)
void gemm_mfma_kernel(const float* __restrict__ H,
                      const unsigned short* __restrict__ WT,
                      unsigned short* __restrict__ HWp) {
    const int tid  = threadIdx.x;
    const int wid  = tid >> 6;
    const int lane = tid & 63;
    const int lrow = lane & 15;
    const int kblk = lane >> 4;
    const int wrow = blockIdx.x * 128 + wid * 32;

    int r0 = wrow + lrow;       if (r0 >= N_NODES) r0 = N_NODES - 1;
    int r1 = wrow + lrow + 16;  if (r1 >= N_NODES) r1 = N_NODES - 1;
    const float* p0 = H + (size_t)r0 * IN_DIM + kblk * 8;
    const float* p1 = H + (size_t)r1 * IN_DIM + kblk * 8;

    f32x4 acc[2][8] = {};

    float4 c00 = *(const float4*)(p0);
    float4 c01 = *(const float4*)(p0 + 4);
    float4 c10 = *(const float4*)(p1);
    float4 c11 = *(const float4*)(p1 + 4);

    #pragma unroll
    for (int kc = 0; kc < 8; ++kc) {
        const s16x8 fa0 = pack8(c00, c01);
        const s16x8 fa1 = pack8(c10, c11);
        if (kc < 7) {
            const float* q0 = p0 + (kc + 1) * 32;
            const float* q1 = p1 + (kc + 1) * 32;
            c00 = *(const float4*)(q0);
            c01 = *(const float4*)(q0 + 4);
            c10 = *(const float4*)(q1);
            c11 = *(const float4*)(q1 + 4);
        }
        const int kbase = kc * 32 + kblk * 8;
        #pragma unroll
        for (int n = 0; n < 8; ++n) {
            const s16x8 fb =
                *(const s16x8*)(WT + (size_t)(n * 16 + lrow) * IN_DIM + kbase);
            acc[0][n] = __builtin_amdgcn_mfma_f32_16x16x32_bf16(fa0, fb, acc[0][n], 0, 0, 0);
            acc[1][n] = __builtin_amdgcn_mfma_f32_16x16x32_bf16(fa1, fb, acc[1][n], 0, 0, 0);
        }
    }

    #pragma unroll
    for (int mt = 0; mt < 2; ++mt) {
        #pragma unroll
        for (int r = 0; r < 4; ++r) {
            const int grow = wrow + mt * 16 + (lane >> 4) * 4 + r;
            if (grow < N_NODES) {
                #pragma unroll
                for (int n = 0; n < 8; ++n)
                    HWp[(size_t)n * (N_NODES * 16) + (size_t)grow * 16 + (lane & 15)] =
                        f2bf_us(acc[mt][n][r]);
            }
        }
    }
}

// ---------------- row_ptr from sorted dst ----------------
__global__ __launch_bounds__(256)
void rowptr_kernel(const int* __restrict__ dst, int* __restrict__ row_ptr) {
    const int e = blockIdx.x * blockDim.x + threadIdx.x;
    if (e > N_EDGES) return;
    if (e == N_EDGES) {
        for (int n = dst[N_EDGES - 1] + 1; n <= N_NODES; ++n) row_ptr[n] = N_EDGES;
        return;
    }
    const int d = dst[e];
    const int dprev = (e == 0) ? -1 : dst[e - 1];
    for (int n = dprev + 1; n <= d; ++n) row_ptr[n] = e;
}

// ---------------- SpMM: out = A @ HW + bias, XCD-pinned column passes --------
// pass = blockIdx.x % 8  -> all blocks of pass p land on XCD p (round-robin
// workgroup dispatch), so XCD p's 4MB L2 only sees slab p (3.2 MB) -> gathers
// become L2 hits. nodeblk = blockIdx.x / 8. Disjoint writes, deterministic.
__global__ __launch_bounds__(256)
void spmm_pass_kernel(const unsigned int* __restrict__ HWpu,
                      const float* __restrict__ vals,
                      const int* __restrict__ src,
                      const int* __restrict__ row_ptr,
                      const float* __restrict__ bias,
                      float* __restrict__ out) {
    const int p    = blockIdx.x & 7;
    const int tid  = threadIdx.x;
    const int node = (blockIdx.x >> 3) * 32 + (tid >> 3);
    const int sub  = tid & 7;
    if (node >= N_NODES) return;

    const unsigned int* __restrict__ slab = HWpu + (size_t)p * (N_NODES * 8);

    const int lo = row_ptr[node];
    const int hi = row_ptr[node + 1];

    float ax = 0.f, ay = 0.f;
    int e = lo;
    for (; e + 8 <= hi; e += 8) {
        int s[8]; float v[8];
        #pragma unroll
        for (int j = 0; j < 8; ++j) { s[j] = src[e + j]; v[j] = vals[e + j]; }
        unsigned u[8];
        #pragma unroll
        for (int j = 0; j < 8; ++j) u[j] = slab[(size_t)s[j] * 8 + sub];
        #pragma unroll
        for (int j = 0; j < 8; ++j) {
            ax = fmaf(__uint_as_float(u[j] << 16), v[j], ax);
            ay = fmaf(__uint_as_float(u[j] & 0xffff0000u), v[j], ay);
        }
    }
    if (e + 4 <= hi) {
        int s[4]; float v[4];
        #pragma unroll
        for (int j = 0; j < 4; ++j) { s[j] = src[e + j]; v[j] = vals[e + j]; }
        unsigned u[4];
        #pragma unroll
        for (int j = 0; j < 4; ++j) u[j] = slab[(size_t)s[j] * 8 + sub];
        #pragma unroll
        for (int j = 0; j < 4; ++j) {
            ax = fmaf(__uint_as_float(u[j] << 16), v[j], ax);
            ay = fmaf(__uint_as_float(u[j] & 0xffff0000u), v[j], ay);
        }
        e += 4;
    }
    for (; e < hi; ++e) {
        const unsigned u = slab[(size_t)src[e] * 8 + sub];
        const float v = vals[e];
        ax = fmaf(__uint_as_float(u << 16), v, ax);
        ay = fmaf(__uint_as_float(u & 0xffff0000u), v, ay);
    }

    const float2 b2 = ((const float2*)bias)[p * 8 + sub];
    ((float2*)out)[(size_t)node * 64 + p * 8 + sub] =
        make_float2(ax + b2.x, ay + b2.y);
}

extern "C" void kernel_launch(void* const* d_in, const int* in_sizes, int n_in,
                              void* d_out, int out_size, void* d_ws, size_t ws_size,
                              hipStream_t stream) {
    const float* H    = (const float*)d_in[0];
    const float* W    = (const float*)d_in[1];
    const float* bias = (const float*)d_in[2];
    const float* vals = (const float*)d_in[3];
    const int*   src  = (const int*)d_in[4];
    const int*   dst  = (const int*)d_in[5];
    float* out = (float*)d_out;

    unsigned short* HWp = (unsigned short*)d_ws;
    const size_t hw_bytes = (size_t)N_NODES * OUT_DIM * sizeof(unsigned short);
    int* row_ptr = (int*)((char*)d_ws + hw_bytes);
    size_t wt_off = hw_bytes + (size_t)(N_NODES + 1) * sizeof(int);
    wt_off = (wt_off + 127) & ~(size_t)127;
    unsigned short* WT = (unsigned short*)((char*)d_ws + wt_off);

    wt_kernel<<<dim3((IN_DIM * OUT_DIM) / 256), dim3(256), 0, stream>>>(W, WT);
    rowptr_kernel<<<dim3((N_EDGES + 256) / 256), dim3(256), 0, stream>>>(dst, row_ptr);
    gemm_mfma_kernel<<<dim3((N_NODES + 127) / 128), dim3(256), 0, stream>>>(H, WT, HWp);

    const int node_blocks = (N_NODES + 31) / 32;          // 3125
    spmm_pass_kernel<<<dim3(node_blocks * 8), dim3(256), 0, stream>>>(
        (const unsigned int*)HWp, vals, src, row_ptr, bias, out);
}

// Round 7
// 130.795 us; speedup vs baseline: 1.3851x; 1.3271x over previous
//
#include <hip/hip_runtime.h>
#include <hip/hip_bf16.h>

#define N_NODES 100000
#define N_EDGES 1600000
#define IN_DIM 256
#define OUT_DIM 128

typedef __attribute__((ext_vector_type(4))) float f32x4;
typedef __attribute__((ext_vector_type(8))) short s16x8;

__device__ inline unsigned short f2bf_us(float f) {
    union { __hip_bfloat16 h; unsigned short u; } v;
    v.h = __float2bfloat16(f);
    return v.u;
}

__device__ inline s16x8 pack8(const float4& a, const float4& b) {
    union { s16x8 v; __hip_bfloat162 h[4]; } u;
    u.h[0] = __float22bfloat162_rn(make_float2(a.x, a.y));
    u.h[1] = __float22bfloat162_rn(make_float2(a.z, a.w));
    u.h[2] = __float22bfloat162_rn(make_float2(b.x, b.y));
    u.h[3] = __float22bfloat162_rn(make_float2(b.z, b.w));
    return u.v;
}

// ---------------- WT = bf16(W^T) : [col][k], 128x256 ----------------
__global__ __launch_bounds__(256)
void wt_kernel(const float* __restrict__ W, unsigned short* __restrict__ WT) {
    const int t = blockIdx.x * 256 + threadIdx.x;   // 0..32767
    const int k = t >> 7;
    const int c = t & 127;
    WT[c * IN_DIM + k] = f2bf_us(W[t]);
}

// ---------------- GEMM: HWb(bf16 row-major) = bf16(H) @ bf16(W) --------------
// NO LDS (graph-replay corruption seen with 67KB LDS in R3). 4 waves/block,
// 128 rows/block. B-frags from WT (64 KB, L2-resident).
__global__ __launch_bounds__(256)
void gemm_mfma_kernel(const float* __restrict__ H,
                      const unsigned short* __restrict__ WT,
                      unsigned short* __restrict__ HWb) {
    const int tid  = threadIdx.x;
    const int wid  = tid >> 6;
    const int lane = tid & 63;
    const int lrow = lane & 15;
    const int kblk = lane >> 4;
    const int wrow = blockIdx.x * 128 + wid * 32;

    int r0 = wrow + lrow;       if (r0 >= N_NODES) r0 = N_NODES - 1;
    int r1 = wrow + lrow + 16;  if (r1 >= N_NODES) r1 = N_NODES - 1;
    const float* p0 = H + (size_t)r0 * IN_DIM + kblk * 8;
    const float* p1 = H + (size_t)r1 * IN_DIM + kblk * 8;

    f32x4 acc[2][8] = {};

    float4 c00 = *(const float4*)(p0);
    float4 c01 = *(const float4*)(p0 + 4);
    float4 c10 = *(const float4*)(p1);
    float4 c11 = *(const float4*)(p1 + 4);

    #pragma unroll
    for (int kc = 0; kc < 8; ++kc) {
        const s16x8 fa0 = pack8(c00, c01);
        const s16x8 fa1 = pack8(c10, c11);
        if (kc < 7) {
            const float* q0 = p0 + (kc + 1) * 32;
            const float* q1 = p1 + (kc + 1) * 32;
            c00 = *(const float4*)(q0);
            c01 = *(const float4*)(q0 + 4);
            c10 = *(const float4*)(q1);
            c11 = *(const float4*)(q1 + 4);
        }
        const int kbase = kc * 32 + kblk * 8;
        #pragma unroll
        for (int n = 0; n < 8; ++n) {
            const s16x8 fb =
                *(const s16x8*)(WT + (size_t)(n * 16 + lrow) * IN_DIM + kbase);
            acc[0][n] = __builtin_amdgcn_mfma_f32_16x16x32_bf16(fa0, fb, acc[0][n], 0, 0, 0);
            acc[1][n] = __builtin_amdgcn_mfma_f32_16x16x32_bf16(fa1, fb, acc[1][n], 0, 0, 0);
        }
    }

    #pragma unroll
    for (int mt = 0; mt < 2; ++mt) {
        #pragma unroll
        for (int r = 0; r < 4; ++r) {
            const int grow = wrow + mt * 16 + (lane >> 4) * 4 + r;
            if (grow < N_NODES) {
                #pragma unroll
                for (int n = 0; n < 8; ++n)
                    HWb[(size_t)grow * OUT_DIM + n * 16 + (lane & 15)] =
                        f2bf_us(acc[mt][n][r]);
            }
        }
    }
}

// ---------------- row_ptr from sorted dst ----------------
__global__ __launch_bounds__(256)
void rowptr_kernel(const int* __restrict__ dst, int* __restrict__ row_ptr) {
    const int e = blockIdx.x * blockDim.x + threadIdx.x;
    if (e > N_EDGES) return;
    if (e == N_EDGES) {
        for (int n = dst[N_EDGES - 1] + 1; n <= N_NODES; ++n) row_ptr[n] = N_EDGES;
        return;
    }
    const int d = dst[e];
    const int dprev = (e == 0) ? -1 : dst[e - 1];
    for (int n = dprev + 1; n <= d; ++n) row_ptr[n] = e;
}

// ---------------- SpMM v3: out = A @ HW(bf16) + bias ----------------
// Wave = 1 node. eslot = lane>>4 (4 edges per gather instr), cg = lane&15
// (16 B of the 256 B row per lane). 4 line-requests/edge (minimum) at 1/4 the
// instruction count of one-edge-per-wave. Unroll x2 -> 8 edges in flight.
// shfl_xor(16,32) reduce; lanes 0..15 store the fp32 row. Deterministic.
__global__ __launch_bounds__(256)
void spmm_v3_kernel(const uint4* __restrict__ HWq, const float* __restrict__ vals,
                    const int* __restrict__ src, const int* __restrict__ row_ptr,
                    const float* __restrict__ bias, float* __restrict__ out) {
    const int node = blockIdx.x * 4 + (threadIdx.x >> 6);
    if (node >= N_NODES) return;
    const int lane  = threadIdx.x & 63;
    const int eslot = lane >> 4;   // 0..3
    const int cg    = lane & 15;   // uint4 (16B) index within 256B row

    const int lo = row_ptr[node];
    const int hi = row_ptr[node + 1];

    float acc[8] = {};
    for (int base = lo; base < hi; base += 8) {
        const int e0 = base + eslot;
        const int e1 = base + 4 + eslot;
        const bool m0 = e0 < hi;
        const bool m1 = e1 < hi;
        const int ec0 = m0 ? e0 : lo;   // lo always valid here (loop ran)
        const int ec1 = m1 ? e1 : lo;
        const int   s0 = src[ec0];
        const int   s1 = src[ec1];
        const float v0 = m0 ? vals[ec0] : 0.f;
        const float v1 = m1 ? vals[ec1] : 0.f;
        const uint4 g0 = HWq[(size_t)s0 * 16 + cg];
        const uint4 g1 = HWq[(size_t)s1 * 16 + cg];

        const unsigned* u0 = (const unsigned*)&g0;
        const unsigned* u1 = (const unsigned*)&g1;
        #pragma unroll
        for (int j = 0; j < 4; ++j) {
            acc[2*j]   = fmaf(__uint_as_float(u0[j] << 16),         v0, acc[2*j]);
            acc[2*j+1] = fmaf(__uint_as_float(u0[j] & 0xffff0000u), v0, acc[2*j+1]);
        }
        #pragma unroll
        for (int j = 0; j < 4; ++j) {
            acc[2*j]   = fmaf(__uint_as_float(u1[j] << 16),         v1, acc[2*j]);
            acc[2*j+1] = fmaf(__uint_as_float(u1[j] & 0xffff0000u), v1, acc[2*j+1]);
        }
    }

    // reduce across the 4 eslot groups (strides 16, 32)
    #pragma unroll
    for (int i = 0; i < 8; ++i) {
        acc[i] += __shfl_xor(acc[i], 16);
        acc[i] += __shfl_xor(acc[i], 32);
    }

    if (lane < 16) {
        float4 o0, o1;
        const float* bb = bias + cg * 8;
        o0.x = acc[0] + bb[0]; o0.y = acc[1] + bb[1];
        o0.z = acc[2] + bb[2]; o0.w = acc[3] + bb[3];
        o1.x = acc[4] + bb[4]; o1.y = acc[5] + bb[5];
        o1.z = acc[6] + bb[6]; o1.w = acc[7] + bb[7];
        float* p = out + (size_t)node * OUT_DIM + cg * 8;
        *(float4*)(p)     = o0;
        *(float4*)(p + 4) = o1;
    }
}

extern "C" void kernel_launch(void* const* d_in, const int* in_sizes, int n_in,
                              void* d_out, int out_size, void* d_ws, size_t ws_size,
                              hipStream_t stream) {
    const float* H    = (const float*)d_in[0];
    const float* W    = (const float*)d_in[1];
    const float* bias = (const float*)d_in[2];
    const float* vals = (const float*)d_in[3];
    const int*   src  = (const int*)d_in[4];
    const int*   dst  = (const int*)d_in[5];
    float* out = (float*)d_out;

    unsigned short* HWb = (unsigned short*)d_ws;   // 25.6 MB bf16 row-major
    const size_t hw_bytes = (size_t)N_NODES * OUT_DIM * sizeof(unsigned short);
    int* row_ptr = (int*)((char*)d_ws + hw_bytes);
    size_t wt_off = hw_bytes + (size_t)(N_NODES + 1) * sizeof(int);
    wt_off = (wt_off + 127) & ~(size_t)127;
    unsigned short* WT = (unsigned short*)((char*)d_ws + wt_off);

    wt_kernel<<<dim3((IN_DIM * OUT_DIM) / 256), dim3(256), 0, stream>>>(W, WT);
    rowptr_kernel<<<dim3((N_EDGES + 256) / 256), dim3(256), 0, stream>>>(dst, row_ptr);
    gemm_mfma_kernel<<<dim3((N_NODES + 127) / 128), dim3(256), 0, stream>>>(H, WT, HWb);
    spmm_v3_kernel<<<dim3((N_NODES + 3) / 4), dim3(256), 0, stream>>>(
        (const uint4*)HWb, vals, src, row_ptr, bias, out);
}